// Round 1
// baseline (7878.545 us; speedup 1.0000x reference)
//
#include <hip/hip_runtime.h>

#define N_ATOMS   200000
#define N_EDGESC  400000
#define ATOM_DIM  133
#define BOND_DIM  14
#define HID       256
#define NGRAPH    8000
#define KI        148   // 147 padded to x4
#define KO        392   // 389 padded to x4
#define EPB       32    // edges/atoms per block in GEMM kernels

// ---------------- weight padding ----------------
__global__ void pad_weights(const float* __restrict__ Wi, const float* __restrict__ Wo,
                            float* __restrict__ Wip, float* __restrict__ Wop) {
    int i = blockIdx.x * blockDim.x + threadIdx.x;
    if (i < HID * KI) {
        int r = i / KI, c = i % KI;
        Wip[i] = (c < 147) ? Wi[r * 147 + c] : 0.f;
        return;
    }
    int j = i - HID * KI;
    if (j < HID * KO) {
        int r = j / KO, c = j % KO;
        Wop[j] = (c < 389) ? Wo[r * 389 + c] : 0.f;
    }
}

// ---------------- CSR build ----------------
__global__ void count_kernel(const int* __restrict__ dst, int* __restrict__ cnt, int n) {
    int i = blockIdx.x * blockDim.x + threadIdx.x;
    if (i < n) atomicAdd(&cnt[dst[i]], 1);
}

// single-block scan: reads deg[], writes offs[] (exclusive) and cursor[] (= offs copy)
__global__ void scan_kernel(const int* deg, int* offs, int* cursor, int n) {
    __shared__ int ssum[1024];
    __shared__ int s_base;
    int tid = threadIdx.x;
    if (tid == 0) s_base = 0;
    __syncthreads();
    const int TPT = 8;
    const int TILE = 1024 * TPT;
    for (int start = 0; start < n; start += TILE) {
        int base_i = start + tid * TPT;
        int v[TPT];
        int s = 0;
#pragma unroll
        for (int j = 0; j < TPT; j++) {
            int i = base_i + j;
            v[j] = (i < n) ? deg[i] : 0;
            s += v[j];
        }
        ssum[tid] = s;
        __syncthreads();
        for (int off = 1; off < 1024; off <<= 1) {
            int x = (tid >= off) ? ssum[tid - off] : 0;
            __syncthreads();
            ssum[tid] += x;
            __syncthreads();
        }
        int thr_excl = ssum[tid] - s;
        int tile_total = ssum[1023];
        int run = s_base + thr_excl;
#pragma unroll
        for (int j = 0; j < TPT; j++) {
            int i = base_i + j;
            if (i < n) { offs[i] = run; cursor[i] = run; run += v[j]; }
        }
        __syncthreads();
        if (tid == 0) s_base += tile_total;
        __syncthreads();
    }
    if (tid == 0) offs[n] = s_base;
}

__global__ void fill_kernel(const int* __restrict__ dst, int* __restrict__ cursor,
                            int* __restrict__ eids, int n) {
    int i = blockIdx.x * blockDim.x + threadIdx.x;
    if (i < n) {
        int p = atomicAdd(&cursor[dst[i]], 1);
        eids[p] = i;
    }
}

// ---------------- h0 = relu([V[src];E] @ W_i^T) ----------------
__global__ void h0_kernel(const float* __restrict__ V, const float* __restrict__ E,
                          const float* __restrict__ Wip, const int* __restrict__ src,
                          float* __restrict__ h0) {
    __shared__ float lin[EPB][KI];
    int e0 = blockIdx.x * EPB;
    int t = threadIdx.x;
    for (int e = 0; e < EPB; e++) {
        int ge = e0 + e;
        int s = src[ge];
        if (t < 133)      lin[e][t] = V[(size_t)s * 133 + t];
        else if (t < 147) lin[e][t] = E[(size_t)ge * 14 + (t - 133)];
        else if (t < KI)  lin[e][t] = 0.f;
    }
    __syncthreads();
    float acc[EPB];
#pragma unroll
    for (int e = 0; e < EPB; e++) acc[e] = 0.f;
    const float4* wrow = (const float4*)&Wip[t * KI];
    for (int kc = 0; kc < KI / 4; kc++) {
        float4 w = wrow[kc];
#pragma unroll
        for (int e = 0; e < EPB; e++) {
            float4 x = *(const float4*)&lin[e][kc * 4];
            acc[e] += w.x * x.x + w.y * x.y + w.z * x.z + w.w * x.w;
        }
    }
#pragma unroll
    for (int e = 0; e < EPB; e++) {
        float r = acc[e] > 0.f ? acc[e] : 0.f;
        h0[(size_t)(e0 + e) * HID + t] = r;
    }
}

// ---------------- m_to_atom[a] = sum_{e: dst[e]==a} w[e]*h[e] ----------------
__global__ void seg_reduce(const float* __restrict__ h, const float* __restrict__ weight,
                           const int* __restrict__ offs, const int* __restrict__ eids,
                           float* __restrict__ out, int weighted) {
    int a = blockIdx.x;
    int t = threadIdx.x;
    int lo = offs[a], hi = offs[a + 1];
    float acc = 0.f;
    for (int i = lo; i < hi; i++) {
        int e = eids[i];
        float w = weighted ? weight[e] : 1.f;
        acc += w * h[(size_t)e * HID + t];
    }
    out[(size_t)a * HID + t] = acc;
}

// ---------------- h_new = relu((mta[src] - w[rev]*h[rev]) @ W_h^T + h0) ----------------
__global__ void mp_kernel(const float* __restrict__ mta, const float* __restrict__ h0,
                          const float* __restrict__ Wh, const float* __restrict__ weight,
                          const int* __restrict__ src, const int* __restrict__ rev,
                          const float* hr, float* hw) {
    __shared__ float lm[EPB][HID];
    int e0 = blockIdx.x * EPB;
    int t = threadIdx.x;
    for (int e = 0; e < EPB; e++) {
        int ge = e0 + e;
        int s = src[ge];
        int r = rev[ge];
        float wr = weight[r];
        lm[e][t] = mta[(size_t)s * HID + t] - wr * hr[(size_t)r * HID + t];
    }
    __syncthreads();   // all reads of old h done before any write (rev stays in-block)
    float acc[EPB];
#pragma unroll
    for (int e = 0; e < EPB; e++) acc[e] = 0.f;
    const float4* wrow = (const float4*)&Wh[t * HID];
    for (int kc = 0; kc < HID / 4; kc++) {
        float4 w = wrow[kc];
#pragma unroll
        for (int e = 0; e < EPB; e++) {
            float4 x = *(const float4*)&lm[e][kc * 4];
            acc[e] += w.x * x.x + w.y * x.y + w.z * x.z + w.w * x.w;
        }
    }
#pragma unroll
    for (int e = 0; e < EPB; e++) {
        size_t idx = (size_t)(e0 + e) * HID + t;
        float v = acc[e] + h0[idx];
        hw[idx] = v > 0.f ? v : 0.f;
    }
}

// ---------------- h_atom = relu([V;m_final] @ W_o^T + b) ----------------
__global__ void out_kernel(const float* __restrict__ V, const float* __restrict__ mfin,
                           const float* __restrict__ Wop, const float* __restrict__ bias,
                           float* __restrict__ h_atom) {
    __shared__ float lin[EPB][KO];
    int a0 = blockIdx.x * EPB;
    int t = threadIdx.x;
    for (int e = 0; e < EPB; e++) {
        int a = a0 + e;
        for (int c = t; c < KO; c += 256) {
            float v;
            if (c < 133)      v = V[(size_t)a * 133 + c];
            else if (c < 389) v = mfin[(size_t)a * HID + (c - 133)];
            else              v = 0.f;
            lin[e][c] = v;
        }
    }
    __syncthreads();
    float acc[EPB];
#pragma unroll
    for (int e = 0; e < EPB; e++) acc[e] = 0.f;
    const float4* wrow = (const float4*)&Wop[t * KO];
    for (int kc = 0; kc < KO / 4; kc++) {
        float4 w = wrow[kc];
#pragma unroll
        for (int e = 0; e < EPB; e++) {
            float4 x = *(const float4*)&lin[e][kc * 4];
            acc[e] += w.x * x.x + w.y * x.y + w.z * x.z + w.w * x.w;
        }
    }
    float b = bias[t];
#pragma unroll
    for (int e = 0; e < EPB; e++) {
        float v = acc[e] + b;
        h_atom[(size_t)(a0 + e) * HID + t] = v > 0.f ? v : 0.f;
    }
}

// ---------------- mol_vecs = segment_sum(h_atom, atom_batch) (sorted) ----------------
__global__ void mol_kernel(const float* __restrict__ h_atom, const int* __restrict__ batch,
                           float* __restrict__ mol) {
    int g = blockIdx.x;
    int t = threadIdx.x;
    __shared__ int s_lo, s_hi;
    if (t == 0) {
        int lo = 0, hi = N_ATOMS;
        while (lo < hi) { int mid = (lo + hi) >> 1; if (batch[mid] < g) lo = mid + 1; else hi = mid; }
        s_lo = lo;
        int lo2 = lo, hi2 = N_ATOMS;
        while (lo2 < hi2) { int mid = (lo2 + hi2) >> 1; if (batch[mid] < g + 1) lo2 = mid + 1; else hi2 = mid; }
        s_hi = lo2;
    }
    __syncthreads();
    float acc = 0.f;
    for (int a = s_lo; a < s_hi; a++) acc += h_atom[(size_t)a * HID + t];
    mol[(size_t)g * HID + t] = acc;
}

__global__ void batchf_kernel(const int* __restrict__ batch, float* __restrict__ outb, int n) {
    int i = blockIdx.x * blockDim.x + threadIdx.x;
    if (i < n) outb[i] = (float)batch[i];
}

extern "C" void kernel_launch(void* const* d_in, const int* in_sizes, int n_in,
                              void* d_out, int out_size, void* d_ws, size_t ws_size,
                              hipStream_t stream) {
    const float* V      = (const float*)d_in[0];
    const float* E      = (const float*)d_in[1];
    const float* weight = (const float*)d_in[2];
    const float* W_i    = (const float*)d_in[3];
    const float* W_h    = (const float*)d_in[4];
    const float* W_o    = (const float*)d_in[5];
    const float* W_b    = (const float*)d_in[6];
    const int*   eidx   = (const int*)d_in[7];
    const int*   src    = eidx;
    const int*   dst    = eidx + N_EDGESC;
    const int*   rev    = (const int*)d_in[8];
    const int*   batch  = (const int*)d_in[9];

    float* out     = (float*)d_out;
    float* o_hatom = out;                                  // 200000*256
    float* o_batch = out + (size_t)51200000;               // 200000
    float* o_mol   = out + (size_t)51400000;               // 8000*256
    float* o_h     = out + (size_t)53448000;               // 400000*256

    char* base = (char*)d_ws;
    float* h0     = (float*)(base);                        // 409,600,000 B
    float* mta    = (float*)(base + 409600000ull);         // 204,800,000 B
    float* Wip    = (float*)(base + 614400000ull);         // 151,552 B
    float* Wop    = (float*)(base + 614551552ull);         // 401,408 B
    int*   offs   = (int*)(base + 614952960ull);           // 800,016 B
    int*   cursor = (int*)(base + 615752976ull);           // 800,000 B
    int*   eids   = (int*)(base + 616552976ull);           // 1,600,000 B

    hipMemsetAsync(cursor, 0, N_ATOMS * sizeof(int), stream);

    {
        int total = HID * KI + HID * KO;
        pad_weights<<<(total + 255) / 256, 256, 0, stream>>>(W_i, W_o, Wip, Wop);
    }
    count_kernel<<<(N_EDGESC + 255) / 256, 256, 0, stream>>>(dst, cursor, N_EDGESC);
    scan_kernel<<<1, 1024, 0, stream>>>(cursor, offs, cursor, N_ATOMS);
    fill_kernel<<<(N_EDGESC + 255) / 256, 256, 0, stream>>>(dst, cursor, eids, N_EDGESC);

    h0_kernel<<<N_EDGESC / EPB, 256, 0, stream>>>(V, E, Wip, src, h0);

    const float* hr = h0;
    for (int it = 0; it < 3; it++) {
        seg_reduce<<<N_ATOMS, 256, 0, stream>>>(hr, weight, offs, eids, mta, 1);
        mp_kernel<<<N_EDGESC / EPB, 256, 0, stream>>>(mta, h0, W_h, weight, src, rev, hr, o_h);
        hr = o_h;
    }

    seg_reduce<<<N_ATOMS, 256, 0, stream>>>(o_h, weight, offs, eids, mta, 0);
    out_kernel<<<N_ATOMS / EPB, 256, 0, stream>>>(V, mta, Wop, W_b, o_hatom);
    mol_kernel<<<NGRAPH, 256, 0, stream>>>(o_hatom, batch, o_mol);
    batchf_kernel<<<(N_ATOMS + 255) / 256, 256, 0, stream>>>(batch, o_batch, N_ATOMS);
}

// Round 4
// 3575.925 us; speedup vs baseline: 2.2032x; 2.2032x over previous
//
#include <hip/hip_runtime.h>

#define N_ATOMS   200000
#define N_EDGESC  400000
#define HID       256
#define NGRAPH    8000

typedef __attribute__((ext_vector_type(8))) short bf16x8;
typedef __attribute__((ext_vector_type(4))) float f32x4;

__device__ inline ushort bfc(float x) {
    union { float f; unsigned u; } u; u.f = x;
    unsigned r = u.u + 0x7fff + ((u.u >> 16) & 1);
    return (ushort)(r >> 16);
}

// ---------------- weight prep: f32 -> bf16 padded layouts ----------------
// Wib: [256][192]  k<133 = Wi[t][k]; 136..149 = Wi[t][133+(k-136)]; else 0
// Whb: [256][256]  direct
// Wob: [256][448]  k<133 = Wo[t][k]; 136..391 = Wo[t][133+(k-136)]; else 0
__global__ void prep_weights(const float* __restrict__ Wi, const float* __restrict__ Wh,
                             const float* __restrict__ Wo, ushort* __restrict__ Wib,
                             ushort* __restrict__ Whb, ushort* __restrict__ Wob) {
    int i = blockIdx.x * 256 + threadIdx.x;
    if (i < 256 * 256) Whb[i] = bfc(Wh[i]);
    if (i < 256 * 192) {
        int t = i / 192, k = i % 192;
        float v = 0.f;
        if (k < 133) v = Wi[t * 147 + k];
        else if (k >= 136 && k < 150) v = Wi[t * 147 + 133 + (k - 136)];
        Wib[i] = bfc(v);
    }
    if (i < 256 * 448) {
        int t = i / 448, k = i % 448;
        float v = 0.f;
        if (k < 133) v = Wo[t * 389 + k];
        else if (k >= 136 && k < 392) v = Wo[t * 389 + 133 + (k - 136)];
        Wob[i] = bfc(v);
    }
}

// ---------------- CSR build ----------------
__global__ void count_kernel(const int* __restrict__ dst, int* __restrict__ cnt, int n) {
    int i = blockIdx.x * blockDim.x + threadIdx.x;
    if (i < n) atomicAdd(&cnt[dst[i]], 1);
}

__global__ void scan_kernel(const int* deg, int* offs, int* cursor, int n) {
    __shared__ int ssum[1024];
    __shared__ int s_base;
    int tid = threadIdx.x;
    if (tid == 0) s_base = 0;
    __syncthreads();
    const int TPT = 8;
    const int TILE = 1024 * TPT;
    for (int start = 0; start < n; start += TILE) {
        int base_i = start + tid * TPT;
        int v[TPT];
        int s = 0;
#pragma unroll
        for (int j = 0; j < TPT; j++) {
            int i = base_i + j;
            v[j] = (i < n) ? deg[i] : 0;
            s += v[j];
        }
        ssum[tid] = s;
        __syncthreads();
        for (int off = 1; off < 1024; off <<= 1) {
            int x = (tid >= off) ? ssum[tid - off] : 0;
            __syncthreads();
            ssum[tid] += x;
            __syncthreads();
        }
        int thr_excl = ssum[tid] - s;
        int tile_total = ssum[1023];
        int run = s_base + thr_excl;
#pragma unroll
        for (int j = 0; j < TPT; j++) {
            int i = base_i + j;
            if (i < n) { offs[i] = run; cursor[i] = run; run += v[j]; }
        }
        __syncthreads();
        if (tid == 0) s_base += tile_total;
        __syncthreads();
    }
    if (tid == 0) offs[n] = s_base;
}

__global__ void fill_kernel(const int* __restrict__ dst, int* __restrict__ cursor,
                            int* __restrict__ eids, int n) {
    int i = blockIdx.x * blockDim.x + threadIdx.x;
    if (i < n) {
        int p = atomicAdd(&cursor[dst[i]], 1);
        eids[p] = i;
    }
}

// h0 = relu([V[src];E] @ Wib^T), K=192, LDS row stride 384B
__global__ __launch_bounds__(256) void h0_mfma(const float* __restrict__ V,
                                               const float* __restrict__ E,
                                               const ushort* __restrict__ Wib,
                                               const int* __restrict__ src,
                                               float* __restrict__ h0) {
    __shared__ char lds[64 * 384];
    int t = threadIdx.x;
    int e0 = blockIdx.x * 64;
#pragma unroll
    for (int i = 0; i < 6; i++) {
        int c = t + i * 256;
        int e = c / 24, kc = c % 24;
        int ge = e0 + e;
        int s = src[ge];
        int k0 = kc * 8;
        bf16x8 v;
#pragma unroll
        for (int j = 0; j < 8; j++) {
            int k = k0 + j;
            float x;
            if (k < 133) x = V[(size_t)s * 133 + k];
            else if (k < 136) x = 0.f;
            else if (k < 150) x = E[(size_t)ge * 14 + (k - 136)];
            else x = 0.f;
            v[j] = (short)bfc(x);
        }
        int addr = (e * 384 + k0 * 2) ^ ((e & 7) << 4);
        *(bf16x8*)(lds + addr) = v;
    }
    __syncthreads();
    int lane = t & 63, w = t >> 6;
    int n0 = w * 64;
    int lq = lane >> 4, lr = lane & 15;
    f32x4 acc[4][4];
#pragma unroll
    for (int mt = 0; mt < 4; mt++)
#pragma unroll
        for (int nt = 0; nt < 4; nt++) acc[mt][nt] = {0.f, 0.f, 0.f, 0.f};
    for (int ks = 0; ks < 6; ks++) {
        int kk = ks * 32 + lq * 8;
        bf16x8 af[4], bfr[4];
#pragma unroll
        for (int mt = 0; mt < 4; mt++) {
            int row = mt * 16 + lr;
            int addr = (row * 384 + kk * 2) ^ ((row & 7) << 4);
            af[mt] = *(const bf16x8*)(lds + addr);
        }
#pragma unroll
        for (int nt = 0; nt < 4; nt++) {
            int col = n0 + nt * 16 + lr;
            bfr[nt] = *(const bf16x8*)&Wib[col * 192 + kk];
        }
#pragma unroll
        for (int mt = 0; mt < 4; mt++)
#pragma unroll
            for (int nt = 0; nt < 4; nt++)
                acc[mt][nt] = __builtin_amdgcn_mfma_f32_16x16x32_bf16(af[mt], bfr[nt], acc[mt][nt], 0, 0, 0);
    }
#pragma unroll
    for (int mt = 0; mt < 4; mt++)
#pragma unroll
        for (int nt = 0; nt < 4; nt++)
#pragma unroll
            for (int j = 0; j < 4; j++) {
                int row = mt * 16 + lq * 4 + j;
                int col = n0 + nt * 16 + lr;
                size_t idx = (size_t)(e0 + row) * HID + col;
                float v = acc[mt][nt][j];
                h0[idx] = v > 0.f ? v : 0.f;
            }
}

// mp: h_new = relu((mta[src] - w[rev]*h[rev]) @ Whb^T + h0), K=256, row stride 512B
__global__ __launch_bounds__(256) void mp_mfma(const float* __restrict__ mta,
                                               const float* __restrict__ h0,
                                               const ushort* __restrict__ Whb,
                                               const float* __restrict__ weight,
                                               const int* __restrict__ src,
                                               const int* __restrict__ rev,
                                               const float* __restrict__ hr,
                                               float* __restrict__ hw) {
    __shared__ char lds[64 * 512];
    int t = threadIdx.x;
    int e0 = blockIdx.x * 64;
    int e = t >> 2, q = t & 3;
    int ge = e0 + e;
    int s = src[ge], r = rev[ge];
    float wr = weight[r];
    const float4* mrow = (const float4*)&mta[(size_t)s * HID];
    const float4* hrow = (const float4*)&hr[(size_t)r * HID];
#pragma unroll
    for (int i = 0; i < 8; i++) {
        int k0 = q * 8 + i * 32;
        float4 a = mrow[k0 / 4], b = mrow[k0 / 4 + 1];
        float4 c = hrow[k0 / 4], d = hrow[k0 / 4 + 1];
        bf16x8 v;
        v[0] = (short)bfc(a.x - wr * c.x);
        v[1] = (short)bfc(a.y - wr * c.y);
        v[2] = (short)bfc(a.z - wr * c.z);
        v[3] = (short)bfc(a.w - wr * c.w);
        v[4] = (short)bfc(b.x - wr * d.x);
        v[5] = (short)bfc(b.y - wr * d.y);
        v[6] = (short)bfc(b.z - wr * d.z);
        v[7] = (short)bfc(b.w - wr * d.w);
        int addr = (e * 512 + k0 * 2) ^ ((e & 7) << 4);
        *(bf16x8*)(lds + addr) = v;
    }
    __syncthreads();   // all reads of old h done before any write (rev stays in-block)
    int lane = t & 63, w = t >> 6;
    int n0 = w * 64;
    int lq = lane >> 4, lr = lane & 15;
    f32x4 acc[4][4];
#pragma unroll
    for (int mt = 0; mt < 4; mt++)
#pragma unroll
        for (int nt = 0; nt < 4; nt++) acc[mt][nt] = {0.f, 0.f, 0.f, 0.f};
    for (int ks = 0; ks < 8; ks++) {
        int kk = ks * 32 + lq * 8;
        bf16x8 af[4], bfr[4];
#pragma unroll
        for (int mt = 0; mt < 4; mt++) {
            int row = mt * 16 + lr;
            int addr = (row * 512 + kk * 2) ^ ((row & 7) << 4);
            af[mt] = *(const bf16x8*)(lds + addr);
        }
#pragma unroll
        for (int nt = 0; nt < 4; nt++) {
            int col = n0 + nt * 16 + lr;
            bfr[nt] = *(const bf16x8*)&Whb[col * 256 + kk];
        }
#pragma unroll
        for (int mt = 0; mt < 4; mt++)
#pragma unroll
            for (int nt = 0; nt < 4; nt++)
                acc[mt][nt] = __builtin_amdgcn_mfma_f32_16x16x32_bf16(af[mt], bfr[nt], acc[mt][nt], 0, 0, 0);
    }
#pragma unroll
    for (int mt = 0; mt < 4; mt++)
#pragma unroll
        for (int nt = 0; nt < 4; nt++)
#pragma unroll
            for (int j = 0; j < 4; j++) {
                int row = mt * 16 + lq * 4 + j;
                int col = n0 + nt * 16 + lr;
                size_t idx = (size_t)(e0 + row) * HID + col;
                float v = acc[mt][nt][j] + h0[idx];
                hw[idx] = v > 0.f ? v : 0.f;
            }
}

// out: h_atom = relu([V;mfin] @ Wob^T + b), K=448, row stride 896B
__global__ __launch_bounds__(256) void out_mfma(const float* __restrict__ V,
                                                const float* __restrict__ mfin,
                                                const ushort* __restrict__ Wob,
                                                const float* __restrict__ bias,
                                                float* __restrict__ h_atom) {
    __shared__ char lds[64 * 896];
    int t = threadIdx.x;
    int a0 = blockIdx.x * 64;
#pragma unroll
    for (int i = 0; i < 14; i++) {
        int c = t + i * 256;
        int e = c / 56, kc = c % 56;
        int a = a0 + e;
        int k0 = kc * 8;
        bf16x8 v;
#pragma unroll
        for (int j = 0; j < 8; j++) {
            int k = k0 + j;
            float x;
            if (k < 133) x = V[(size_t)a * 133 + k];
            else if (k < 136) x = 0.f;
            else if (k < 392) x = mfin[(size_t)a * HID + (k - 136)];
            else x = 0.f;
            v[j] = (short)bfc(x);
        }
        int addr = (e * 896 + k0 * 2) ^ ((e & 7) << 4);
        *(bf16x8*)(lds + addr) = v;
    }
    __syncthreads();
    int lane = t & 63, w = t >> 6;
    int n0 = w * 64;
    int lq = lane >> 4, lr = lane & 15;
    f32x4 acc[4][4];
#pragma unroll
    for (int mt = 0; mt < 4; mt++)
#pragma unroll
        for (int nt = 0; nt < 4; nt++) acc[mt][nt] = {0.f, 0.f, 0.f, 0.f};
    for (int ks = 0; ks < 14; ks++) {
        int kk = ks * 32 + lq * 8;
        bf16x8 af[4], bfr[4];
#pragma unroll
        for (int mt = 0; mt < 4; mt++) {
            int row = mt * 16 + lr;
            int addr = (row * 896 + kk * 2) ^ ((row & 7) << 4);
            af[mt] = *(const bf16x8*)(lds + addr);
        }
#pragma unroll
        for (int nt = 0; nt < 4; nt++) {
            int col = n0 + nt * 16 + lr;
            bfr[nt] = *(const bf16x8*)&Wob[col * 448 + kk];
        }
#pragma unroll
        for (int mt = 0; mt < 4; mt++)
#pragma unroll
            for (int nt = 0; nt < 4; nt++)
                acc[mt][nt] = __builtin_amdgcn_mfma_f32_16x16x32_bf16(af[mt], bfr[nt], acc[mt][nt], 0, 0, 0);
    }
#pragma unroll
    for (int mt = 0; mt < 4; mt++)
#pragma unroll
        for (int nt = 0; nt < 4; nt++)
#pragma unroll
            for (int j = 0; j < 4; j++) {
                int row = mt * 16 + lq * 4 + j;
                int col = n0 + nt * 16 + lr;
                size_t idx = (size_t)(a0 + row) * HID + col;
                float v = acc[mt][nt][j] + bias[col];
                h_atom[idx] = v > 0.f ? v : 0.f;
            }
}

// ---------------- m_to_atom: float4, 4 atoms per block ----------------
__global__ void seg_reduce(const float* __restrict__ h, const float* __restrict__ weight,
                           const int* __restrict__ offs, const int* __restrict__ eids,
                           float* __restrict__ out, int weighted) {
    int t = threadIdx.x;
    int a = blockIdx.x * 4 + (t >> 6);
    int c4 = t & 63;
    int lo = offs[a], hi = offs[a + 1];
    float4 acc = {0.f, 0.f, 0.f, 0.f};
    for (int i = lo; i < hi; i++) {
        int e = eids[i];
        float w = weighted ? weight[e] : 1.f;
        float4 x = ((const float4*)&h[(size_t)e * HID])[c4];
        acc.x += w * x.x; acc.y += w * x.y; acc.z += w * x.z; acc.w += w * x.w;
    }
    ((float4*)&out[(size_t)a * HID])[c4] = acc;
}

// ---------------- mol_vecs ----------------
__global__ void mol_kernel(const float* __restrict__ h_atom, const int* __restrict__ batch,
                           float* __restrict__ mol) {
    int g = blockIdx.x;
    int t = threadIdx.x;
    __shared__ int s_lo, s_hi;
    if (t == 0) {
        int lo = 0, hi = N_ATOMS;
        while (lo < hi) { int mid = (lo + hi) >> 1; if (batch[mid] < g) lo = mid + 1; else hi = mid; }
        s_lo = lo;
        int lo2 = lo, hi2 = N_ATOMS;
        while (lo2 < hi2) { int mid = (lo2 + hi2) >> 1; if (batch[mid] < g + 1) lo2 = mid + 1; else hi2 = mid; }
        s_hi = lo2;
    }
    __syncthreads();
    float acc = 0.f;
    for (int a = s_lo; a < s_hi; a++) acc += h_atom[(size_t)a * HID + t];
    mol[(size_t)g * HID + t] = acc;
}

__global__ void batchf_kernel(const int* __restrict__ batch, float* __restrict__ outb, int n) {
    int i = blockIdx.x * blockDim.x + threadIdx.x;
    if (i < n) outb[i] = (float)batch[i];
}

extern "C" void kernel_launch(void* const* d_in, const int* in_sizes, int n_in,
                              void* d_out, int out_size, void* d_ws, size_t ws_size,
                              hipStream_t stream) {
    const float* V      = (const float*)d_in[0];
    const float* E      = (const float*)d_in[1];
    const float* weight = (const float*)d_in[2];
    const float* W_i    = (const float*)d_in[3];
    const float* W_h    = (const float*)d_in[4];
    const float* W_o    = (const float*)d_in[5];
    const float* W_b    = (const float*)d_in[6];
    const int*   eidx   = (const int*)d_in[7];
    const int*   src    = eidx;
    const int*   dst    = eidx + N_EDGESC;
    const int*   rev    = (const int*)d_in[8];
    const int*   batch  = (const int*)d_in[9];

    float* out     = (float*)d_out;
    float* o_hatom = out;                                  // 200000*256
    float* o_batch = out + (size_t)51200000;               // 200000
    float* o_mol   = out + (size_t)51400000;               // 8000*256
    float* o_h     = out + (size_t)53448000;               // 400000*256

    char* base = (char*)d_ws;
    float*  h0     = (float*)(base);                       // 409,600,000 B
    float*  mta    = (float*)(base + 409600000ull);        // 204,800,000 B
    ushort* Whb    = (ushort*)(base + 614400000ull);       // 131,072 B
    ushort* Wib    = (ushort*)(base + 614531072ull);       // 98,304 B
    ushort* Wob    = (ushort*)(base + 614629376ull);       // 229,376 B
    int*    offs   = (int*)(base + 614858752ull);          // 800,016 B
    int*    cursor = (int*)(base + 615658768ull);          // 800,000 B
    int*    eids   = (int*)(base + 616458768ull);          // 1,600,000 B

    hipMemsetAsync(cursor, 0, N_ATOMS * sizeof(int), stream);

    prep_weights<<<448, 256, 0, stream>>>(W_i, W_h, W_o, Wib, Whb, Wob);
    count_kernel<<<(N_EDGESC + 255) / 256, 256, 0, stream>>>(dst, cursor, N_EDGESC);
    scan_kernel<<<1, 1024, 0, stream>>>(cursor, offs, cursor, N_ATOMS);
    fill_kernel<<<(N_EDGESC + 255) / 256, 256, 0, stream>>>(dst, cursor, eids, N_EDGESC);

    h0_mfma<<<N_EDGESC / 64, 256, 0, stream>>>(V, E, Wib, src, h0);

    const float* hr = h0;
    for (int it = 0; it < 3; it++) {
        seg_reduce<<<N_ATOMS / 4, 256, 0, stream>>>(hr, weight, offs, eids, mta, 1);
        mp_mfma<<<N_EDGESC / 64, 256, 0, stream>>>(mta, h0, Whb, weight, src, rev, hr, o_h);
        hr = o_h;
    }

    seg_reduce<<<N_ATOMS / 4, 256, 0, stream>>>(o_h, weight, offs, eids, mta, 0);
    out_mfma<<<N_ATOMS / 64, 256, 0, stream>>>(V, mta, Wob, W_b, o_hatom);
    mol_kernel<<<NGRAPH, 256, 0, stream>>>(o_hatom, batch, o_mol);
    batchf_kernel<<<(N_ATOMS + 255) / 256, 256, 0, stream>>>(batch, o_batch, N_ATOMS);
}

// Round 6
// 2752.664 us; speedup vs baseline: 2.8622x; 1.2991x over previous
//
#include <hip/hip_runtime.h>

#define N_ATOMS   200000
#define N_EDGESC  400000
#define HID       256
#define NGRAPH    8000

typedef __attribute__((ext_vector_type(8))) short bf16x8;
typedef __attribute__((ext_vector_type(8))) unsigned short u16x8;
typedef __attribute__((ext_vector_type(4))) unsigned short u16x4;
typedef __attribute__((ext_vector_type(4))) float f32x4;

__device__ inline ushort bfc(float x) {
    union { float f; unsigned u; } u; u.f = x;
    unsigned r = u.u + 0x7fff + ((u.u >> 16) & 1);
    return (ushort)(r >> 16);
}
__device__ inline float b2f(ushort u) {
    union { unsigned u; float f; } x; x.u = ((unsigned)u) << 16; return x.f;
}

// ---------------- weight prep: f32 -> bf16 padded layouts ----------------
__global__ void prep_weights(const float* __restrict__ Wi, const float* __restrict__ Wh,
                             const float* __restrict__ Wo, ushort* __restrict__ Wib,
                             ushort* __restrict__ Whb, ushort* __restrict__ Wob) {
    int i = blockIdx.x * 256 + threadIdx.x;
    if (i < 256 * 256) Whb[i] = bfc(Wh[i]);
    if (i < 256 * 192) {
        int t = i / 192, k = i % 192;
        float v = 0.f;
        if (k < 133) v = Wi[t * 147 + k];
        else if (k >= 136 && k < 150) v = Wi[t * 147 + 133 + (k - 136)];
        Wib[i] = bfc(v);
    }
    if (i < 256 * 448) {
        int t = i / 448, k = i % 448;
        float v = 0.f;
        if (k < 133) v = Wo[t * 389 + k];
        else if (k >= 136 && k < 392) v = Wo[t * 389 + 133 + (k - 136)];
        Wob[i] = bfc(v);
    }
}

// ---------------- CSR build ----------------
__global__ void count_kernel(const int* __restrict__ dst, int* __restrict__ cnt, int n) {
    int i = blockIdx.x * blockDim.x + threadIdx.x;
    if (i < n) atomicAdd(&cnt[dst[i]], 1);
}

__global__ void scan_kernel(const int* deg, int* offs, int* cursor, int n) {
    __shared__ int ssum[1024];
    __shared__ int s_base;
    int tid = threadIdx.x;
    if (tid == 0) s_base = 0;
    __syncthreads();
    const int TPT = 8;
    const int TILE = 1024 * TPT;
    for (int start = 0; start < n; start += TILE) {
        int base_i = start + tid * TPT;
        int v[TPT];
        int s = 0;
#pragma unroll
        for (int j = 0; j < TPT; j++) {
            int i = base_i + j;
            v[j] = (i < n) ? deg[i] : 0;
            s += v[j];
        }
        ssum[tid] = s;
        __syncthreads();
        for (int off = 1; off < 1024; off <<= 1) {
            int x = (tid >= off) ? ssum[tid - off] : 0;
            __syncthreads();
            ssum[tid] += x;
            __syncthreads();
        }
        int thr_excl = ssum[tid] - s;
        int tile_total = ssum[1023];
        int run = s_base + thr_excl;
#pragma unroll
        for (int j = 0; j < TPT; j++) {
            int i = base_i + j;
            if (i < n) { offs[i] = run; cursor[i] = run; run += v[j]; }
        }
        __syncthreads();
        if (tid == 0) s_base += tile_total;
        __syncthreads();
    }
    if (tid == 0) offs[n] = s_base;
}

__global__ void fill_kernel(const int* __restrict__ dst, int* __restrict__ cursor,
                            int* __restrict__ eids, int n) {
    int i = blockIdx.x * blockDim.x + threadIdx.x;
    if (i < n) {
        int p = atomicAdd(&cursor[dst[i]], 1);
        eids[p] = i;
    }
}

// h0 = relu([V[src];E] @ Wib^T), K=192, LDS row stride 384B. Output bf16.
__global__ __launch_bounds__(256) void h0_mfma(const float* __restrict__ V,
                                               const float* __restrict__ E,
                                               const ushort* __restrict__ Wib,
                                               const int* __restrict__ src,
                                               ushort* __restrict__ h0b) {
    __shared__ char lds[64 * 384];
    int t = threadIdx.x;
    int e0 = blockIdx.x * 64;
#pragma unroll
    for (int i = 0; i < 6; i++) {
        int c = t + i * 256;
        int e = c / 24, kc = c % 24;
        int ge = e0 + e;
        int s = src[ge];
        int k0 = kc * 8;
        bf16x8 v;
#pragma unroll
        for (int j = 0; j < 8; j++) {
            int k = k0 + j;
            float x;
            if (k < 133) x = V[(size_t)s * 133 + k];
            else if (k < 136) x = 0.f;
            else if (k < 150) x = E[(size_t)ge * 14 + (k - 136)];
            else x = 0.f;
            v[j] = (short)bfc(x);
        }
        int addr = (e * 384 + k0 * 2) ^ ((e & 7) << 4);
        *(bf16x8*)(lds + addr) = v;
    }
    __syncthreads();
    int lane = t & 63, w = t >> 6;
    int n0 = w * 64;
    int lq = lane >> 4, lr = lane & 15;
    f32x4 acc[4][4];
#pragma unroll
    for (int mt = 0; mt < 4; mt++)
#pragma unroll
        for (int nt = 0; nt < 4; nt++) acc[mt][nt] = {0.f, 0.f, 0.f, 0.f};
    for (int ks = 0; ks < 6; ks++) {
        int kk = ks * 32 + lq * 8;
        bf16x8 af[4], bfr[4];
#pragma unroll
        for (int mt = 0; mt < 4; mt++) {
            int row = mt * 16 + lr;
            int addr = (row * 384 + kk * 2) ^ ((row & 7) << 4);
            af[mt] = *(const bf16x8*)(lds + addr);
        }
#pragma unroll
        for (int nt = 0; nt < 4; nt++) {
            int col = n0 + nt * 16 + lr;
            bfr[nt] = *(const bf16x8*)&Wib[col * 192 + kk];
        }
#pragma unroll
        for (int mt = 0; mt < 4; mt++)
#pragma unroll
            for (int nt = 0; nt < 4; nt++)
                acc[mt][nt] = __builtin_amdgcn_mfma_f32_16x16x32_bf16(af[mt], bfr[nt], acc[mt][nt], 0, 0, 0);
    }
#pragma unroll
    for (int mt = 0; mt < 4; mt++)
#pragma unroll
        for (int nt = 0; nt < 4; nt++)
#pragma unroll
            for (int j = 0; j < 4; j++) {
                int row = mt * 16 + lq * 4 + j;
                int col = n0 + nt * 16 + lr;
                size_t idx = (size_t)(e0 + row) * HID + col;
                float v = acc[mt][nt][j];
                h0b[idx] = bfc(v > 0.f ? v : 0.f);
            }
}

// mp: h_new = relu((mta[src] - w[rev]*h[rev]) @ Whb^T + h0)
// bf16 inputs; FINAL=0 writes bf16 h, FINAL=1 writes f32 o_h.
template <int FINAL>
__global__ __launch_bounds__(256) void mp_mfma(const ushort* __restrict__ mta_b,
                                               const ushort* __restrict__ h0b,
                                               const ushort* __restrict__ Whb,
                                               const float* __restrict__ weight,
                                               const int* __restrict__ src,
                                               const int* __restrict__ rev,
                                               const ushort* __restrict__ hr_b,
                                               ushort* __restrict__ hw_b,
                                               float* __restrict__ hw_f) {
    __shared__ char lds[64 * 512];
    int t = threadIdx.x;
    int e0 = blockIdx.x * 64;
    int e = t >> 2, q = t & 3;
    int ge = e0 + e;
    int s = src[ge], r = rev[ge];
    float wr = weight[r];
    const u16x8* mrow = (const u16x8*)&mta_b[(size_t)s * HID];  // 32 chunks of 8 bf16
    const u16x8* hrow = (const u16x8*)&hr_b[(size_t)r * HID];
    u16x8 ma[8], ha[8];
#pragma unroll
    for (int i = 0; i < 8; i++) ma[i] = mrow[q + i * 4];   // issue all loads first
#pragma unroll
    for (int i = 0; i < 8; i++) ha[i] = hrow[q + i * 4];
#pragma unroll
    for (int i = 0; i < 8; i++) {
        int chunk = q + i * 4;
        u16x8 v;
#pragma unroll
        for (int j = 0; j < 8; j++)
            v[j] = bfc(b2f(ma[i][j]) - wr * b2f(ha[i][j]));
        int addr = (e * 512 + chunk * 16) ^ ((e & 7) << 4);
        *(u16x8*)(lds + addr) = v;
    }
    __syncthreads();   // all reads of old h done before any write (rev stays in-block)
    int lane = t & 63, w = t >> 6;
    int n0 = w * 64;
    int lq = lane >> 4, lr = lane & 15;
    f32x4 acc[4][4];
#pragma unroll
    for (int mt = 0; mt < 4; mt++)
#pragma unroll
        for (int nt = 0; nt < 4; nt++) acc[mt][nt] = {0.f, 0.f, 0.f, 0.f};
    for (int ks = 0; ks < 8; ks++) {
        int kk = ks * 32 + lq * 8;
        bf16x8 af[4], bfr[4];
#pragma unroll
        for (int mt = 0; mt < 4; mt++) {
            int row = mt * 16 + lr;
            int addr = (row * 512 + kk * 2) ^ ((row & 7) << 4);
            af[mt] = *(const bf16x8*)(lds + addr);
        }
#pragma unroll
        for (int nt = 0; nt < 4; nt++) {
            int col = n0 + nt * 16 + lr;
            bfr[nt] = *(const bf16x8*)&Whb[col * 256 + kk];
        }
#pragma unroll
        for (int mt = 0; mt < 4; mt++)
#pragma unroll
            for (int nt = 0; nt < 4; nt++)
                acc[mt][nt] = __builtin_amdgcn_mfma_f32_16x16x32_bf16(af[mt], bfr[nt], acc[mt][nt], 0, 0, 0);
    }
#pragma unroll
    for (int mt = 0; mt < 4; mt++)
#pragma unroll
        for (int nt = 0; nt < 4; nt++)
#pragma unroll
            for (int j = 0; j < 4; j++) {
                int row = mt * 16 + lq * 4 + j;
                int col = n0 + nt * 16 + lr;
                size_t idx = (size_t)(e0 + row) * HID + col;
                float v = acc[mt][nt][j] + b2f(h0b[idx]);
                v = v > 0.f ? v : 0.f;
                if (FINAL) hw_f[idx] = v;
                else       hw_b[idx] = bfc(v);
            }
}

// out: h_atom = relu([V;mfin] @ Wob^T + b), K=448, mfin is bf16, output f32
__global__ __launch_bounds__(256) void out_mfma(const float* __restrict__ V,
                                                const ushort* __restrict__ mfin,
                                                const ushort* __restrict__ Wob,
                                                const float* __restrict__ bias,
                                                float* __restrict__ h_atom) {
    __shared__ char lds[64 * 896];
    int t = threadIdx.x;
    int a0 = blockIdx.x * 64;
#pragma unroll
    for (int i = 0; i < 14; i++) {
        int c = t + i * 256;
        int e = c / 56, kc = c % 56;
        int a = a0 + e;
        int k0 = kc * 8;
        u16x8 v;
#pragma unroll
        for (int j = 0; j < 8; j++) {
            int k = k0 + j;
            ushort x;
            if (k < 133) x = bfc(V[(size_t)a * 133 + k]);
            else if (k < 136) x = 0;
            else if (k < 392) x = mfin[(size_t)a * HID + (k - 136)];
            else x = 0;
            v[j] = x;
        }
        int addr = (e * 896 + k0 * 2) ^ ((e & 7) << 4);
        *(u16x8*)(lds + addr) = v;
    }
    __syncthreads();
    int lane = t & 63, w = t >> 6;
    int n0 = w * 64;
    int lq = lane >> 4, lr = lane & 15;
    f32x4 acc[4][4];
#pragma unroll
    for (int mt = 0; mt < 4; mt++)
#pragma unroll
        for (int nt = 0; nt < 4; nt++) acc[mt][nt] = {0.f, 0.f, 0.f, 0.f};
    for (int ks = 0; ks < 14; ks++) {
        int kk = ks * 32 + lq * 8;
        bf16x8 af[4], bfr[4];
#pragma unroll
        for (int mt = 0; mt < 4; mt++) {
            int row = mt * 16 + lr;
            int addr = (row * 896 + kk * 2) ^ ((row & 7) << 4);
            af[mt] = *(const bf16x8*)(lds + addr);
        }
#pragma unroll
        for (int nt = 0; nt < 4; nt++) {
            int col = n0 + nt * 16 + lr;
            bfr[nt] = *(const bf16x8*)&Wob[col * 448 + kk];
        }
#pragma unroll
        for (int mt = 0; mt < 4; mt++)
#pragma unroll
            for (int nt = 0; nt < 4; nt++)
                acc[mt][nt] = __builtin_amdgcn_mfma_f32_16x16x32_bf16(af[mt], bfr[nt], acc[mt][nt], 0, 0, 0);
    }
#pragma unroll
    for (int mt = 0; mt < 4; mt++)
#pragma unroll
        for (int nt = 0; nt < 4; nt++)
#pragma unroll
            for (int j = 0; j < 4; j++) {
                int row = mt * 16 + lq * 4 + j;
                int col = n0 + nt * 16 + lr;
                size_t idx = (size_t)(a0 + row) * HID + col;
                float v = acc[mt][nt][j] + bias[col];
                h_atom[idx] = v > 0.f ? v : 0.f;
            }
}

// ---------------- seg reduce: bf16 in (weighted), bf16 out; wave per atom ----
__global__ void seg_reduce_b(const ushort* __restrict__ h, const float* __restrict__ weight,
                             const int* __restrict__ offs, const int* __restrict__ eids,
                             ushort* __restrict__ out) {
    int t = threadIdx.x;
    int a = blockIdx.x * 4 + (t >> 6);
    int c = t & 63;
    int lo = offs[a], hi = offs[a + 1];
    float acc0 = 0.f, acc1 = 0.f, acc2 = 0.f, acc3 = 0.f;
    for (int i = lo; i < hi; i++) {
        int e = eids[i];
        float w = weight[e];
        u16x4 x = ((const u16x4*)&h[(size_t)e * HID])[c];
        acc0 += w * b2f(x[0]); acc1 += w * b2f(x[1]);
        acc2 += w * b2f(x[2]); acc3 += w * b2f(x[3]);
    }
    u16x4 o; o[0] = bfc(acc0); o[1] = bfc(acc1); o[2] = bfc(acc2); o[3] = bfc(acc3);
    ((u16x4*)&out[(size_t)a * HID])[c] = o;
}

// final: f32 in (unweighted), bf16 out
__global__ void seg_reduce_f(const float* __restrict__ h,
                             const int* __restrict__ offs, const int* __restrict__ eids,
                             ushort* __restrict__ out) {
    int t = threadIdx.x;
    int a = blockIdx.x * 4 + (t >> 6);
    int c = t & 63;
    int lo = offs[a], hi = offs[a + 1];
    float4 acc = {0.f, 0.f, 0.f, 0.f};
    for (int i = lo; i < hi; i++) {
        int e = eids[i];
        float4 x = ((const float4*)&h[(size_t)e * HID])[c];
        acc.x += x.x; acc.y += x.y; acc.z += x.z; acc.w += x.w;
    }
    u16x4 o; o[0] = bfc(acc.x); o[1] = bfc(acc.y); o[2] = bfc(acc.z); o[3] = bfc(acc.w);
    ((u16x4*)&out[(size_t)a * HID])[c] = o;
}

// ---------------- mol_vecs ----------------
__global__ void mol_kernel(const float* __restrict__ h_atom, const int* __restrict__ batch,
                           float* __restrict__ mol) {
    int g = blockIdx.x;
    int t = threadIdx.x;
    __shared__ int s_lo, s_hi;
    if (t == 0) {
        int lo = 0, hi = N_ATOMS;
        while (lo < hi) { int mid = (lo + hi) >> 1; if (batch[mid] < g) lo = mid + 1; else hi = mid; }
        s_lo = lo;
        int lo2 = lo, hi2 = N_ATOMS;
        while (lo2 < hi2) { int mid = (lo2 + hi2) >> 1; if (batch[mid] < g + 1) lo2 = mid + 1; else hi2 = mid; }
        s_hi = lo2;
    }
    __syncthreads();
    float acc = 0.f;
    for (int a = s_lo; a < s_hi; a++) acc += h_atom[(size_t)a * HID + t];
    mol[(size_t)g * HID + t] = acc;
}

__global__ void batchf_kernel(const int* __restrict__ batch, float* __restrict__ outb, int n) {
    int i = blockIdx.x * blockDim.x + threadIdx.x;
    if (i < n) outb[i] = (float)batch[i];
}

extern "C" void kernel_launch(void* const* d_in, const int* in_sizes, int n_in,
                              void* d_out, int out_size, void* d_ws, size_t ws_size,
                              hipStream_t stream) {
    const float* V      = (const float*)d_in[0];
    const float* E      = (const float*)d_in[1];
    const float* weight = (const float*)d_in[2];
    const float* W_i    = (const float*)d_in[3];
    const float* W_h    = (const float*)d_in[4];
    const float* W_o    = (const float*)d_in[5];
    const float* W_b    = (const float*)d_in[6];
    const int*   eidx   = (const int*)d_in[7];
    const int*   src    = eidx;
    const int*   dst    = eidx + N_EDGESC;
    const int*   rev    = (const int*)d_in[8];
    const int*   batch  = (const int*)d_in[9];

    float* out     = (float*)d_out;
    float* o_hatom = out;                                  // 200000*256
    float* o_batch = out + (size_t)51200000;               // 200000
    float* o_mol   = out + (size_t)51400000;               // 8000*256
    float* o_h     = out + (size_t)53448000;               // 400000*256

    char* base = (char*)d_ws;
    ushort* h0b    = (ushort*)(base);                      // 204,800,000 B
    ushort* h_b    = (ushort*)(base + 204800000ull);       // 204,800,000 B
    ushort* mta_b  = (ushort*)(base + 409600000ull);       // 102,400,000 B
    ushort* Whb    = (ushort*)(base + 512000000ull);       // 131,072 B
    ushort* Wib    = (ushort*)(base + 512131072ull);       // 98,304 B
    ushort* Wob    = (ushort*)(base + 512229376ull);       // 229,376 B
    int*    offs   = (int*)(base + 512458752ull);          // 800,016 B
    int*    cursor = (int*)(base + 513258768ull);          // 800,000 B
    int*    eids   = (int*)(base + 514058768ull);          // 1,600,000 B

    hipMemsetAsync(cursor, 0, N_ATOMS * sizeof(int), stream);

    prep_weights<<<448, 256, 0, stream>>>(W_i, W_h, W_o, Wib, Whb, Wob);
    count_kernel<<<(N_EDGESC + 255) / 256, 256, 0, stream>>>(dst, cursor, N_EDGESC);
    scan_kernel<<<1, 1024, 0, stream>>>(cursor, offs, cursor, N_ATOMS);
    fill_kernel<<<(N_EDGESC + 255) / 256, 256, 0, stream>>>(dst, cursor, eids, N_EDGESC);

    h0_mfma<<<N_EDGESC / 64, 256, 0, stream>>>(V, E, Wib, src, h0b);

    // it 0: hr=h0b -> h_b ; it 1: h_b -> h_b (in place, race-free) ; it 2: h_b -> o_h (f32)
    seg_reduce_b<<<N_ATOMS / 4, 256, 0, stream>>>(h0b, weight, offs, eids, mta_b);
    mp_mfma<0><<<N_EDGESC / 64, 256, 0, stream>>>(mta_b, h0b, Whb, weight, src, rev, h0b, h_b, nullptr);

    seg_reduce_b<<<N_ATOMS / 4, 256, 0, stream>>>(h_b, weight, offs, eids, mta_b);
    mp_mfma<0><<<N_EDGESC / 64, 256, 0, stream>>>(mta_b, h0b, Whb, weight, src, rev, h_b, h_b, nullptr);

    seg_reduce_b<<<N_ATOMS / 4, 256, 0, stream>>>(h_b, weight, offs, eids, mta_b);
    mp_mfma<1><<<N_EDGESC / 64, 256, 0, stream>>>(mta_b, h0b, Whb, weight, src, rev, h_b, nullptr, o_h);

    seg_reduce_f<<<N_ATOMS / 4, 256, 0, stream>>>(o_h, offs, eids, mta_b);
    out_mfma<<<N_ATOMS / 64, 256, 0, stream>>>(V, mta_b, Wob, W_b, o_hatom);
    mol_kernel<<<NGRAPH, 256, 0, stream>>>(o_hatom, batch, o_mol);
    batchf_kernel<<<(N_ATOMS + 255) / 256, 256, 0, stream>>>(batch, o_batch, N_ATOMS);
}